// Round 5
// baseline (515.348 us; speedup 1.0000x reference)
//
#include <hip/hip_runtime.h>

// ---------------------------------------------------------------------------
// B=4, S=4096, D=1024 linear attention (phi = elu+1), bf16 MFMA GEMMs.
// R3: BK=64 K-loop + XOR-swizzled LDS, algebraic reorder out = z*(q@(kv@Wo)).
// R5: modes 0/6/8 on 256x256 8-phase schedule — 100.8us, MfmaUtil 27.5%.
// R7: cross-phase A-reuse (-33% LDS reads) — 95.2us (-6%): LDS BW not binding.
// R8: de-serialize the phase. ONE s_barrier per phase (8/iter, was 16);
//     manual lgkmcnt(0)+sched_barrier REMOVED (reads are compiler-visible;
//     compiler emits fine-grained lgkmcnt per MFMA dependency and may
//     overlap read-issue with MFMA-issue); Gray-code quadrant walk
//     (00->01->11->10): reads/phase 12,4,8,0 (48/iter). Stage slots and
//     VMW values (4/6/4/6, tail 0@ph4) unchanged — ledger re-verified
//     event-by-event under the new barrier positions.
// ---------------------------------------------------------------------------

typedef __bf16 bf16x8 __attribute__((ext_vector_type(8)));
typedef __bf16 bf16x4 __attribute__((ext_vector_type(4)));
typedef float  f32x4  __attribute__((ext_vector_type(4)));

#define GLOBAL_AS __attribute__((address_space(1)))
#define LDS_AS    __attribute__((address_space(3)))

#define SS 4096
#define DD 1024

__device__ __forceinline__ __bf16 f2bf(float f) {
  union { float f; unsigned u; } a; a.f = f;
  unsigned r = a.u + 0x7FFFu + ((a.u >> 16) & 1u);   // RNE (no NaN inputs here)
  union { unsigned short s; __bf16 b; } o; o.s = (unsigned short)(r >> 16);
  return o.b;
}

__device__ __forceinline__ void async_load16(const void* g, void* l) {
  __builtin_amdgcn_global_load_lds((const GLOBAL_AS void*)g, (LDS_AS void*)l, 16, 0, 0);
}

// ===========================================================================
// 256x256-tile 8-phase GEMM: C[m][n] = sum_k A[m][k] * BT[n][k]
// 512 threads = 8 waves (2M x 4N); per-wave out 128x64 (acc[8][4] f32x4).
// LDS 128 KB: A0|A1|B0|B1 tiles of 256 rows x 64 (bf16), XOR-chunk swizzle.
// Phase: {VMW?; stage (2 global_load_lds); ds_reads; s_barrier;
//         setprio(1) 16 MFMA setprio(0)}   — ONE barrier per phase.
// Gray-code walk per buffer X/Y: (0,0)->(0,1)->(1,1)->(1,0); b(nh0) and
// b1(nh1) held in regs across phases; a re-read per m-half.
// Stage slots/iter i: ph1 A1h1(2i+1) ph2 B1h1(2i+1) ph3 A0h0(2i+2)
//   ph4 B0h0(2i+2) ph5 A0h1(2i+2) ph6 B0h1(2i+2) ph7 A1h0(2i+3)
//   ph8 B1h0(2i+3).
// vmcnt ledger (each VMW is separated from the reads it protects by >=1
// barrier): ph1 VMW(4) retires prev ph5/ph6 stages (covers ph2 B0h1, ph3
// A0h1); ph4 VMW(6) retires prev ph7/ph8 (covers ph5 A1h0/B1h0); ph5
// VMW(4) retires ph1/ph2 (covers ph6 B1h1, ph7 A1h1); ph8 VMW(6) retires
// ph3/ph4 (covers next ph1 A0h0/B0h0). Tail drains with VMW(0) at ph4.
// MODE: 0 = bias+phi->bf16 row-major (q)
//       6 = fused k/v, TRANSPOSED dual output -> kphiT/vT [b][D][S]
//       8 = z*acc + bias + residual -> f32 (final; B operand per-batch)
// ===========================================================================

#define LA0 0
#define LA1 16384
#define LB0 32768
#define LB1 49152

#define VMW(n)  asm volatile("s_waitcnt vmcnt(" #n ")" ::: "memory")
#define SBAR()  asm volatile("s_barrier" ::: "memory")

#define STG_A(BASE, mh, kt) do {                                              \
    async_load16(Aa + (long)((mh)*64 + t6) * K + (kt)*64 + gc8,               \
                 smem + (BASE) + (mh)*8192 + tid*8);                          \
    async_load16(Aa + (long)(128 + (mh)*64 + t6) * K + (kt)*64 + gc8,         \
                 smem + (BASE) + (mh)*8192 + 4096 + tid*8);                   \
  } while (0)

#define STG_B(BASE, nh, kt) do {                                              \
    async_load16(Bb + (long)(tA*64 + (nh)*32 + t5) * K + (kt)*64 + gc8,       \
                 smem + (BASE) + (nh)*8192 + tid*8);                          \
    async_load16(Bb + (long)(128 + tA*64 + (nh)*32 + t5) * K + (kt)*64 + gc8, \
                 smem + (BASE) + (nh)*8192 + 4096 + tid*8);                   \
  } while (0)

#define RD_A(dst, AB, mh)                                                     \
    _Pragma("unroll") for (int rr = 0; rr < 4; ++rr) {                        \
      const int o = (AB) + (mh)*8192 + rr*1024 + aoff;                        \
      dst[rr][0] = *(const bf16x8*)(smem + o);                                \
      dst[rr][1] = *(const bf16x8*)(smem + (o ^ 32));                         \
    }

#define RD_B(dst, BB, nh)                                                     \
    _Pragma("unroll") for (int nn = 0; nn < 2; ++nn) {                        \
      const int o = (BB) + (nh)*8192 + nn*1024 + boff;                        \
      dst[nn][0] = *(const bf16x8*)(smem + o);                                \
      dst[nn][1] = *(const bf16x8*)(smem + (o ^ 32));                         \
    }

#define MM(mh, nh, af, bf)                                                    \
    __builtin_amdgcn_s_setprio(1);                                            \
    _Pragma("unroll") for (int rr = 0; rr < 4; ++rr)                          \
    _Pragma("unroll") for (int nn = 0; nn < 2; ++nn) {                        \
      acc[(mh)*4+rr][(nh)*2+nn] = __builtin_amdgcn_mfma_f32_16x16x32_bf16(    \
          af[rr][0], bf[nn][0], acc[(mh)*4+rr][(nh)*2+nn], 0, 0, 0);          \
      acc[(mh)*4+rr][(nh)*2+nn] = __builtin_amdgcn_mfma_f32_16x16x32_bf16(    \
          af[rr][1], bf[nn][1], acc[(mh)*4+rr][(nh)*2+nn], 0, 0, 0);          \
    }                                                                         \
    __builtin_amdgcn_s_setprio(0)

#define PH(VM, STG, RDS, MMM) do {                                            \
    VM; STG; RDS;                                                             \
    SBAR();                                                                   \
    MMM;                                                                      \
  } while (0)

template<int MODE>
__global__ __launch_bounds__(512, 2)
void gemm256(const __bf16* __restrict__ Ag, const __bf16* __restrict__ Bg,
             void* __restrict__ Cg, void* __restrict__ Cg2,
             int N, int K, long sB,
             const float* __restrict__ bias, const float* __restrict__ bias2,
             const float* __restrict__ zvec, const float* __restrict__ resid)
{
  union SMem {
    __bf16 st[65536];        // 128 KB staging: A0 A1 B0 B1
    __bf16 T[256 * 136];     // mode-6 transpose epilogue (69.6 KB)
  };
  __shared__ SMem sm;
  __bf16* smem = sm.st;

  // XCD-aware swizzle: same-by (shared A-panel) blocks land on one XCD.
  int bx = blockIdx.x, by = blockIdx.y;
  {
    const int gx = gridDim.x, gy = gridDim.y;
    if ((gy & 7) == 0) {
      const int f = by * gx + bx;
      const int j = f & 7;
      const int u = f >> 3;
      bx = u % gx;
      by = j * (gy >> 3) + u / gx;
    }
  }

  const int tid  = threadIdx.x;
  const int lane = tid & 63, wave = tid >> 6;
  const int wm   = wave >> 2, wn = wave & 3;
  const int ln   = lane & 15, quad = lane >> 4;
  const int t6   = tid >> 3, tA = t6 >> 5, t5 = t6 & 31;
  const int gc8  = ((tid & 7) ^ (t6 & 7)) * 8;
  const int pco  = (quad ^ (ln & 7)) * 8;
  const int aoff = (wm * 64 + ln) * 64 + pco;
  const int boff = (wn * 32 + ln) * 64 + pco;

  const long m0  = (long)by * 256;
  const int  n0g = bx * 256;
  const __bf16* Aa = Ag + m0 * K;
  const __bf16* Bb = Bg + (long)bx * 256 * K +
                     ((MODE == 8) ? (long)(m0 >> 12) * sB : 0);

  f32x4 acc[8][4];
  const f32x4 zero = {0.f, 0.f, 0.f, 0.f};
#pragma unroll
  for (int i = 0; i < 8; i++)
#pragma unroll
    for (int j = 0; j < 4; j++) acc[i][j] = zero;

  // prologue: kt0 full (A0,B0 both halves) + kt1 (A1h0,B1h0) = 12 loads
  STG_A(LA0, 0, 0); STG_B(LB0, 0, 0);
  STG_A(LA0, 1, 0); STG_B(LB0, 1, 0);
  STG_A(LA1, 0, 1); STG_B(LB1, 0, 1);
  VMW(8);           // kt0 A0h0/B0h0 landed
  SBAR();

  const int niter = K >> 7;            // 2 K-tiles (of 64) per iteration
#pragma unroll 1
  for (int i = 0; i < niter - 1; ++i) {
    const int kb = i * 2;
    bf16x8 a[4][2], b[2][2], b1[2][2];
    PH(VMW(4), STG_A(LA1,1,kb+1), RD_A(a,LA0,0) RD_B(b,LB0,0), MM(0,0,a,b));
    PH(      , STG_B(LB1,1,kb+1), RD_B(b1,LB0,1),              MM(0,1,a,b1));
    PH(      , STG_A(LA0,0,kb+2), RD_A(a,LA0,1),               MM(1,1,a,b1));
    PH(VMW(6), STG_B(LB0,0,kb+2), ,                            MM(1,0,a,b));
    PH(VMW(4), STG_A(LA0,1,kb+2), RD_A(a,LA1,0) RD_B(b,LB1,0), MM(0,0,a,b));
    PH(      , STG_B(LB0,1,kb+2), RD_B(b1,LB1,1),              MM(0,1,a,b1));
    PH(      , STG_A(LA1,0,kb+3), RD_A(a,LA1,1),               MM(1,1,a,b1));
    PH(VMW(6), STG_B(LB1,0,kb+3), ,                            MM(1,0,a,b));
  }
  { // peeled last iteration: no stages beyond kt = 2*niter-1; drain at ph4
    const int kb = (niter - 1) * 2;
    bf16x8 a[4][2], b[2][2], b1[2][2];
    PH(VMW(4), STG_A(LA1,1,kb+1), RD_A(a,LA0,0) RD_B(b,LB0,0), MM(0,0,a,b));
    PH(      , STG_B(LB1,1,kb+1), RD_B(b1,LB0,1),              MM(0,1,a,b1));
    PH(      , ,                  RD_A(a,LA0,1),               MM(1,1,a,b1));
    PH(VMW(0), ,                  ,                            MM(1,0,a,b));
    PH(      , ,                  RD_A(a,LA1,0) RD_B(b,LB1,0), MM(0,0,a,b));
    PH(      , ,                  RD_B(b1,LB1,1),              MM(0,1,a,b1));
    PH(      , ,                  RD_A(a,LA1,1),               MM(1,1,a,b1));
    PH(      , ,                  ,                            MM(1,0,a,b));
    SBAR();   // all waves' K-loop LDS reads done before epilogue reuses LDS
  }

  // epilogue: C/D layout col = lane&15, row = quad*4 + reg (m89-verified)
  if (MODE == 6) {
    // transposed dual store: per m-half pass, tile -> LDS [n][s] -> [d][s]
    const bool isK = (n0g < 1024);
    const float* bb = isK ? bias : bias2;
    const int nb = isK ? n0g : (n0g - 1024);
    const int b = (int)(m0 >> 12);
    const long s_in = m0 & 4095;
    __bf16* dst = (__bf16*)(isK ? Cg : Cg2) + (long)b * DD * SS;
#pragma unroll
    for (int h = 0; h < 2; ++h) {
      if (wm == h) {
#pragma unroll
        for (int mf = 0; mf < 8; ++mf)
#pragma unroll
          for (int nf = 0; nf < 4; ++nf) {
            const int nl = wn * 64 + nf * 16 + ln;      // 0..255
            const int sl0 = mf * 16 + quad * 4;         // 0..124, mult of 4
            const float bv = bb[nb + nl];
            bf16x4 pk;
#pragma unroll
            for (int r = 0; r < 4; ++r) {
              float x = acc[mf][nf][r] + bv;
              if (isK) x = (x > 0.f) ? (x + 1.f) : __expf(x);
              pk[r] = f2bf(x);
            }
            *(bf16x4*)(sm.T + nl * 136 + sl0) = pk;     // 8B aligned (136*2B)
          }
      }
      __syncthreads();
#pragma unroll
      for (int p2 = 0; p2 < 8; ++p2) {
        const int row = (tid >> 4) + p2 * 32;           // n within tile
        const int c   = (tid & 15) * 8;                 // s chunk (128 wide)
        bf16x8 vv = *(const bf16x8*)(sm.T + row * 136 + c);
        *(bf16x8*)&dst[(long)(nb + row) * SS + s_in + h * 128 + c] = vv;
      }
      __syncthreads();
    }
    return;
  }

#pragma unroll
  for (int mf = 0; mf < 8; ++mf)
#pragma unroll
    for (int nf = 0; nf < 4; ++nf)
#pragma unroll
      for (int r = 0; r < 4; ++r) {
        const long gm = m0 + wm * 128 + mf * 16 + quad * 4 + r;
        const int  gn = n0g + wn * 64 + nf * 16 + ln;
        float x = acc[mf][nf][r];
        if (MODE == 0) {
          x += bias[gn];
          x = (x > 0.f) ? (x + 1.f) : __expf(x);
          ((__bf16*)Cg)[gm * (long)N + gn] = f2bf(x);
        } else {           // MODE 8
          x = x * zvec[gm] + bias[gn];
          ((float*)Cg)[gm * (long)N + gn] = x + resid[gm * (long)N + gn];
        }
      }
}

#undef PH
#undef MM
#undef RD_A
#undef RD_B
#undef STG_A
#undef STG_B

// ---------------------------------------------------------------------------
// 128x128-tile GEMM (2-barrier structure) — kept for modes 5 and 7.
// MODE: 5 = split-K(4) fp32 atomicAdd partials (kv)
//       7 = plain->bf16 (M2 = kv@Wo, stored as M2T[f][d])
// ---------------------------------------------------------------------------
template<int MODE>
__global__ __launch_bounds__(256)
void gemm_bt(const __bf16* __restrict__ Ag, const __bf16* __restrict__ Bg,
             void* __restrict__ Cg, void* __restrict__ Cg2,
             int N, int K, long sA, long sB, long sC,
             const float* __restrict__ bias, const float* __restrict__ bias2,
             const float* __restrict__ zvec,
             const float* __restrict__ resid)
{
  union SMem {
    struct { __bf16 As[128 * 64]; __bf16 Bs[128 * 64]; } s;  // 32 KB
    __bf16 T[128 * 136];                                     // 34 KB (epilogue)
  };
  __shared__ SMem sm;

  int bx = blockIdx.x, by = blockIdx.y;
  {
    const int gx = gridDim.x, gy = gridDim.y;
    if ((gy & 7) == 0) {
      const int f = by * gx + bx;
      const int j = f & 7;
      const int u = f >> 3;
      bx = u % gx;
      by = j * (gy >> 3) + u / gx;
    }
  }
  int bz = blockIdx.z;
  int k0beg = 0, k0end = K;
  if (MODE == 5) {               // z = batch*4 + split
    const int split = bz & 3;
    bz >>= 2;
    k0beg = split * (K >> 2);
    k0end = k0beg + (K >> 2);
  }

  const int tid = threadIdx.x;
  const long m0 = (long)by * 128;
  const __bf16* A = Ag + m0 * K + bz * sA;
  const __bf16* B = Bg + (long)bx * 128 * K + bz * sB;

  const int srow = tid >> 3;                   // 0..31
  const int gcc8 = ((tid & 7) ^ (srow & 7)) * 8;

  const int lane = tid & 63;
  const int wave = tid >> 6;
  const int wm   = (wave >> 1) * 64;
  const int wn   = (wave & 1) * 64;
  const int ln   = lane & 15;
  const int quad = lane >> 4;
  const int rk   = ln & 7;

  f32x4 acc[4][4];
  const f32x4 zero = {0.f, 0.f, 0.f, 0.f};
#pragma unroll
  for (int i = 0; i < 4; i++)
#pragma unroll
    for (int j = 0; j < 4; j++) acc[i][j] = zero;

  for (int k0 = k0beg; k0 < k0end; k0 += 64) {
#pragma unroll
    for (int p = 0; p < 4; p++) {
      async_load16(A + (long)(p * 32 + srow) * K + k0 + gcc8, sm.s.As + p * 2048 + tid * 8);
      async_load16(B + (long)(p * 32 + srow) * K + k0 + gcc8, sm.s.Bs + p * 2048 + tid * 8);
    }
    __syncthreads();

#pragma unroll
    for (int ksub = 0; ksub < 2; ksub++) {
      const int cc = (ksub * 4 + quad) ^ rk;
      bf16x8 af[4], bfr[4];
#pragma unroll
      for (int i = 0; i < 4; i++)
        af[i] = *(const bf16x8*)(sm.s.As + (wm + i * 16 + ln) * 64 + cc * 8);
#pragma unroll
      for (int j = 0; j < 4; j++)
        bfr[j] = *(const bf16x8*)(sm.s.Bs + (wn + j * 16 + ln) * 64 + cc * 8);
#pragma unroll
      for (int i = 0; i < 4; i++)
#pragma unroll
        for (int j = 0; j < 4; j++)
          acc[i][j] = __builtin_amdgcn_mfma_f32_16x16x32_bf16(af[i], bfr[j], acc[i][j], 0, 0, 0);
    }
    __syncthreads();
  }

  const int n0g = bx * 128;
#pragma unroll
  for (int i = 0; i < 4; i++) {
#pragma unroll
    for (int j = 0; j < 4; j++) {
#pragma unroll
      for (int r = 0; r < 4; r++) {
        const int lrow = wm + i * 16 + quad * 4 + r;
        const int lcol = wn + j * 16 + ln;
        const long gm  = m0 + lrow;
        const int  gn  = n0g + lcol;
        float x = acc[i][j][r];
        if (MODE == 5) {
          __hip_atomic_fetch_add(&((float*)Cg)[(long)bz * sC + gm * (long)N + gn],
                                 x, __ATOMIC_RELAXED, __HIP_MEMORY_SCOPE_AGENT);
        } else if (MODE == 7) {
          ((__bf16*)Cg)[(long)bz * sC + gm * (long)N + gn] = f2bf(x);
        }
      }
    }
  }
}

// ---------------------------------------------------------------------------
__global__ __launch_bounds__(256)
void cvt_f32_bf16(const float* __restrict__ x, __bf16* __restrict__ y, long n)
{
  long i = ((long)blockIdx.x * 256 + threadIdx.x) * 4;
  if (i < n) {
    float4 v = *(const float4*)(x + i);
    bf16x4 o;
    o[0] = f2bf(v.x); o[1] = f2bf(v.y); o[2] = f2bf(v.z); o[3] = f2bf(v.w);
    *(bf16x4*)(y + i) = o;
  }
}

// ---------------------------------------------------------------------------
// Weight transpose + convert: W fp32 [D][D] -> WT bf16 [D][D]; 4 weights via z
// ---------------------------------------------------------------------------
__global__ __launch_bounds__(256)
void wtrans(const float* W0, const float* W1, const float* W2, const float* W3,
            __bf16* O0, __bf16* O1, __bf16* O2, __bf16* O3, int Dd)
{
  __shared__ __bf16 t[64][72];
  const float* W = (blockIdx.z == 0) ? W0 : (blockIdx.z == 1) ? W1 : (blockIdx.z == 2) ? W2 : W3;
  __bf16*      O = (blockIdx.z == 0) ? O0 : (blockIdx.z == 1) ? O1 : (blockIdx.z == 2) ? O2 : O3;
  const int r0 = blockIdx.y * 64, c0 = blockIdx.x * 64;
  const int tid = threadIdx.x;
  const int lr4 = tid >> 4, lc4 = (tid & 15) * 4;
#pragma unroll
  for (int it = 0; it < 4; it++) {
    const int row = lr4 + it * 16;
    float4 v = *(const float4*)&W[(long)(r0 + row) * Dd + c0 + lc4];
    t[row][lc4 + 0] = f2bf(v.x);
    t[row][lc4 + 1] = f2bf(v.y);
    t[row][lc4 + 2] = f2bf(v.z);
    t[row][lc4 + 3] = f2bf(v.w);
  }
  __syncthreads();
  const int lr8 = tid >> 3, lc8 = (tid & 7) * 8;
#pragma unroll
  for (int it = 0; it < 2; it++) {
    const int orow = lr8 + it * 32;
    bf16x8 vb;
#pragma unroll
    for (int j = 0; j < 8; j++) vb[j] = t[lc8 + j][orow];
    *(bf16x8*)&O[(long)(c0 + orow) * Dd + r0 + lc8] = vb;
  }
}

// ---------------------------------------------------------------------------
// k_sum[b*D+d] = sum_s kphiT[(b*D+d)*S + s]
// ---------------------------------------------------------------------------
__global__ __launch_bounds__(256)
void ksum_k(const __bf16* __restrict__ kphiT, float* __restrict__ ksum, int S)
{
  const long row = blockIdx.x;
  const __bf16* p = kphiT + row * (long)S;
  const int tid = threadIdx.x;
  float s = 0.f;
  for (int j = tid * 8; j < S; j += 256 * 8) {
    bf16x8 v = *(const bf16x8*)&p[j];
#pragma unroll
    for (int e = 0; e < 8; e++) s += (float)v[e];
  }
  __shared__ float red[256];
  red[tid] = s; __syncthreads();
  for (int off = 128; off > 0; off >>= 1) {
    if (tid < off) red[tid] += red[tid + off];
    __syncthreads();
  }
  if (tid == 0) ksum[row] = red[0];
}

// ---------------------------------------------------------------------------
// z[b*S+s] = 1 / (q_phi[row] . k_sum[b] + 1e-6)
// ---------------------------------------------------------------------------
__global__ __launch_bounds__(256)
void zden_k(const __bf16* __restrict__ qphi, const float* __restrict__ ksum,
            float* __restrict__ z, int Dd, int S)
{
  const long row = blockIdx.x;
  const int  b   = (int)(row / S);
  const __bf16* q = qphi + row * (long)Dd;
  const float* ks = ksum + (long)b * Dd;
  const int tid = threadIdx.x;
  const int i = tid * 4;                      // Dd = 1024 = 256*4 exactly
  bf16x4 qv = *(const bf16x4*)&q[i];
  float4 kv4 = *(const float4*)&ks[i];
  float s = (float)qv[0] * kv4.x + (float)qv[1] * kv4.y +
            (float)qv[2] * kv4.z + (float)qv[3] * kv4.w;
  __shared__ float red[256];
  red[tid] = s; __syncthreads();
  for (int off = 128; off > 0; off >>= 1) {
    if (tid < off) red[tid] += red[tid + off];
    __syncthreads();
  }
  if (tid == 0) z[row] = 1.f / (red[0] + 1e-6f);
}

// ---------------------------------------------------------------------------
extern "C" void kernel_launch(void* const* d_in, const int* in_sizes, int n_in,
                              void* d_out, int out_size, void* d_ws, size_t ws_size,
                              hipStream_t stream)
{
  const float* inputs  = (const float*)d_in[0];
  const float* context = (const float*)d_in[1];
  const float* Wq = (const float*)d_in[2];
  const float* bq = (const float*)d_in[3];
  const float* Wk = (const float*)d_in[4];
  const float* bk = (const float*)d_in[5];
  const float* Wv = (const float*)d_in[6];
  const float* bv = (const float*)d_in[7];
  const float* Wo = (const float*)d_in[8];
  const float* bo = (const float*)d_in[9];
  float* out = (float*)d_out;

  const int Bn = 4;
  const long NSD = (long)Bn * SS * DD;         // 16,777,216
  const long MB = 1L << 20;

  char* ws = (char*)d_ws;
  __bf16* xbf   = (__bf16*)(ws + 0 * MB);      // 32 MB
  __bf16* cbf   = (__bf16*)(ws + 32 * MB);     // 32 MB
  __bf16* qphi  = (__bf16*)(ws + 64 * MB);     // 32 MB
  __bf16* kphiT = (__bf16*)(ws + 96 * MB);     // 32 MB   [b][D][S]
  __bf16* vT    = (__bf16*)(ws + 128 * MB);    // 32 MB   [b][D][S]
  float*  kvf   = (float*)(ws + 160 * MB);     // 16 MB   [b][D][D] fp32
  __bf16* kvbf  = (__bf16*)(ws + 176 * MB);    // 8 MB    [b][D][D]
  __bf16* M2T   = (__bf16*)(ws + 184 * MB);    // 8 MB    [b][D][D]  (kv@Wo)^T
  __bf16* WqT   = (__bf16*)(ws + 192 * MB);    // 2 MB each; WkT/WvT contiguous!
  __bf16* WkT   = (__bf16*)(ws + 194 * MB);
  __bf16* WvT   = (__bf16*)(ws + 196 * MB);
  __bf16* WoT   = (__bf16*)(ws + 198 * MB);
  float*  ksum  = (float*)(ws + 200 * MB);
  float*  zbuf  = (float*)(ws + 201 * MB);

  // 1) converts
  cvt_f32_bf16<<<16384, 256, 0, stream>>>(inputs,  xbf, NSD);
  cvt_f32_bf16<<<16384, 256, 0, stream>>>(context, cbf, NSD);
  wtrans<<<dim3(16, 16, 4), 256, 0, stream>>>(Wq, Wk, Wv, Wo, WqT, WkT, WvT, WoT, DD);

  // 2) q projection: qphi = phi(x Wq + bq), row-major [B*S][D]
  gemm256<0><<<dim3(4, 64), 512, 0, stream>>>(xbf, WqT, qphi, nullptr,
      DD, DD, 0, bq, nullptr, nullptr, nullptr);

  // 3) fused k/v projection (N=2048, WkT||WvT contiguous), transposed outputs
  gemm256<6><<<dim3(8, 64), 512, 0, stream>>>(cbf, WkT, kphiT, vT,
      2048, DD, 0, bk, bv, nullptr, nullptr);

  // 4) k_sum and z
  ksum_k<<<4096, 256, 0, stream>>>(kphiT, ksum, SS);
  zden_k<<<16384, 256, 0, stream>>>(qphi, ksum, zbuf, DD, SS);

  // 5) kv[b][d][e] = sum_s kphiT[b][d][s] * vT[b][e][s], split-K(4) fp32 atomics
  hipMemsetAsync(kvf, 0, (size_t)Bn * DD * DD * sizeof(float), stream);
  gemm_bt<5><<<dim3(8, 8, 16), 256, 0, stream>>>(kphiT, vT, kvf, nullptr,
      DD, SS, (long)DD * SS, (long)DD * SS, (long)DD * DD,
      nullptr, nullptr, nullptr, nullptr);
  cvt_f32_bf16<<<4096, 256, 0, stream>>>(kvf, kvbf, (long)Bn * DD * DD);

  // 6) M2T[b][f][d] = sum_e WoT[f][e] * kv[b][d][e]   (tiny: 8.6 GF)
  gemm_bt<7><<<dim3(8, 8, 4), 256, 0, stream>>>(WoT, kvbf, M2T, nullptr,
      DD, DD, 0, (long)DD * DD, (long)DD * DD, nullptr, nullptr, nullptr, nullptr);

  // 7) out[s][f] = z[s] * (sum_d qphi[s][d] * M2T[b][f][d]) + bo[f] + x[s][f]
  gemm256<8><<<dim3(4, 64), 512, 0, stream>>>(qphi, M2T, out, nullptr,
      DD, DD, (long)DD * DD, bo, nullptr, zbuf, inputs);
}

// Round 6
// 462.773 us; speedup vs baseline: 1.1136x; 1.1136x over previous
//
#include <hip/hip_runtime.h>

// ---------------------------------------------------------------------------
// B=4, S=4096, D=1024 linear attention (phi = elu+1), bf16 MFMA GEMMs.
// R3: BK=64 K-loop + XOR-swizzled LDS, algebraic reorder out = z*(q@(kv@Wo)).
// R5: modes 0/6/8 on 256x256 8-phase schedule — 100.8us, MfmaUtil 27.5%.
// R7: cross-phase A-reuse (-33% LDS reads) — 95.2us (-6%): LDS BW not binding.
// R8: ONE s_barrier per phase + Gray-code walk — gemm256 dropped below 92us.
// R9: kv GEMM (old gemm_bt<5>, 92us, atomic split-K, MfmaUtil 14.5%) moved to
//     gemm256 8-phase: grid 4x4x16 (batch*4+split), Klen=1024/split, PLAIN f32
//     partial stores (no atomics -> no 64MB RMW reads), partials in the dead
//     xbf/cbf region (64MB), reduce4_bf16 folds 4 partials -> kvbf. Band
//     remap: XCD j owns v in [32j,32j+32) (bx fastest) -> A/B panel L2 reuse.
//     memset removed. Schedule/ledger of gemm256 unchanged.
// ---------------------------------------------------------------------------

typedef __bf16 bf16x8 __attribute__((ext_vector_type(8)));
typedef __bf16 bf16x4 __attribute__((ext_vector_type(4)));
typedef float  f32x4  __attribute__((ext_vector_type(4)));

#define GLOBAL_AS __attribute__((address_space(1)))
#define LDS_AS    __attribute__((address_space(3)))

#define SS 4096
#define DD 1024

__device__ __forceinline__ __bf16 f2bf(float f) {
  union { float f; unsigned u; } a; a.f = f;
  unsigned r = a.u + 0x7FFFu + ((a.u >> 16) & 1u);   // RNE (no NaN inputs here)
  union { unsigned short s; __bf16 b; } o; o.s = (unsigned short)(r >> 16);
  return o.b;
}

__device__ __forceinline__ void async_load16(const void* g, void* l) {
  __builtin_amdgcn_global_load_lds((const GLOBAL_AS void*)g, (LDS_AS void*)l, 16, 0, 0);
}

// ===========================================================================
// 256x256-tile 8-phase GEMM: C[m][n] = sum_k A[m][k] * BT[n][k]
// 512 threads = 8 waves (2M x 4N); per-wave out 128x64 (acc[8][4] f32x4).
// LDS 128 KB: A0|A1|B0|B1 tiles of 256 rows x 64 (bf16), XOR-chunk swizzle.
// Phase: {VMW?; stage (2 global_load_lds); ds_reads; s_barrier;
//         setprio(1) 16 MFMA setprio(0)}   — ONE barrier per phase.
// Gray-code walk per buffer X/Y: (0,0)->(0,1)->(1,1)->(1,0); b(nh0) and
// b1(nh1) held in regs across phases; a re-read per m-half.
// vmcnt ledger (each VMW separated from the reads it protects by >=1
// barrier): ph1 VMW(4); ph4 VMW(6); ph5 VMW(4); ph8 VMW(6); tail VMW(0)@ph4.
// K = row stride (elements); Klen = contraction length for this launch.
// MODE: 0 = bias+phi->bf16 row-major (q)
//       5 = kv split-K partials: z=batch*4+split, plain f32 store slab z
//       6 = fused k/v, TRANSPOSED dual output -> kphiT/vT [b][D][S]
//       8 = z*acc + bias + residual -> f32 (final; B operand per-batch)
// ===========================================================================

#define LA0 0
#define LA1 16384
#define LB0 32768
#define LB1 49152

#define VMW(n)  asm volatile("s_waitcnt vmcnt(" #n ")" ::: "memory")
#define SBAR()  asm volatile("s_barrier" ::: "memory")

#define STG_A(BASE, mh, kt) do {                                              \
    async_load16(Aa + (long)((mh)*64 + t6) * K + (kt)*64 + gc8,               \
                 smem + (BASE) + (mh)*8192 + tid*8);                          \
    async_load16(Aa + (long)(128 + (mh)*64 + t6) * K + (kt)*64 + gc8,         \
                 smem + (BASE) + (mh)*8192 + 4096 + tid*8);                   \
  } while (0)

#define STG_B(BASE, nh, kt) do {                                              \
    async_load16(Bb + (long)(tA*64 + (nh)*32 + t5) * K + (kt)*64 + gc8,       \
                 smem + (BASE) + (nh)*8192 + tid*8);                          \
    async_load16(Bb + (long)(128 + tA*64 + (nh)*32 + t5) * K + (kt)*64 + gc8, \
                 smem + (BASE) + (nh)*8192 + 4096 + tid*8);                   \
  } while (0)

#define RD_A(dst, AB, mh)                                                     \
    _Pragma("unroll") for (int rr = 0; rr < 4; ++rr) {                        \
      const int o = (AB) + (mh)*8192 + rr*1024 + aoff;                        \
      dst[rr][0] = *(const bf16x8*)(smem + o);                                \
      dst[rr][1] = *(const bf16x8*)(smem + (o ^ 32));                         \
    }

#define RD_B(dst, BB, nh)                                                     \
    _Pragma("unroll") for (int nn = 0; nn < 2; ++nn) {                        \
      const int o = (BB) + (nh)*8192 + nn*1024 + boff;                        \
      dst[nn][0] = *(const bf16x8*)(smem + o);                                \
      dst[nn][1] = *(const bf16x8*)(smem + (o ^ 32));                         \
    }

#define MM(mh, nh, af, bf)                                                    \
    __builtin_amdgcn_s_setprio(1);                                            \
    _Pragma("unroll") for (int rr = 0; rr < 4; ++rr)                          \
    _Pragma("unroll") for (int nn = 0; nn < 2; ++nn) {                        \
      acc[(mh)*4+rr][(nh)*2+nn] = __builtin_amdgcn_mfma_f32_16x16x32_bf16(    \
          af[rr][0], bf[nn][0], acc[(mh)*4+rr][(nh)*2+nn], 0, 0, 0);          \
      acc[(mh)*4+rr][(nh)*2+nn] = __builtin_amdgcn_mfma_f32_16x16x32_bf16(    \
          af[rr][1], bf[nn][1], acc[(mh)*4+rr][(nh)*2+nn], 0, 0, 0);          \
    }                                                                         \
    __builtin_amdgcn_s_setprio(0)

#define PH(VM, STG, RDS, MMM) do {                                            \
    VM; STG; RDS;                                                             \
    SBAR();                                                                   \
    MMM;                                                                      \
  } while (0)

template<int MODE>
__global__ __launch_bounds__(512, 2)
void gemm256(const __bf16* __restrict__ Ag, const __bf16* __restrict__ Bg,
             void* __restrict__ Cg, void* __restrict__ Cg2,
             int N, int K, int Klen, long sA, long sB,
             const float* __restrict__ bias, const float* __restrict__ bias2,
             const float* __restrict__ zvec, const float* __restrict__ resid)
{
  union SMem {
    __bf16 st[65536];        // 128 KB staging: A0 A1 B0 B1
    __bf16 T[256 * 136];     // mode-6 transpose epilogue (69.6 KB)
  };
  __shared__ SMem sm;
  __bf16* smem = sm.st;

  int bx = blockIdx.x, by = blockIdx.y;
  int zid = 0;
  long koff = 0, abat = 0, bbat = 0;
  if (MODE == 5) {
    // band remap: linear dispatch id l (x fastest) has XCD = l%8 [m09].
    // Give XCD j the contiguous band v in [32j, 32j+32), bx fastest ->
    // the 4 bx-blocks sharing an A-panel are co-resident on one XCD.
    const int l = ((int)blockIdx.z * (int)gridDim.y + (int)blockIdx.y)
                  * (int)gridDim.x + (int)blockIdx.x;
    const int v = (l & 7) * 32 + (l >> 3);     // 256 blocks total
    bx = v & 3; by = (v >> 2) & 3; zid = v >> 4;        // zid = batch*4+split
    koff = (long)(zid & 3) * 1024;
    abat = (long)(zid >> 2) * sA;
    bbat = (long)(zid >> 2) * sB;
  } else {
    // XCD-aware swizzle for 2D grids (gy % 8 == 0)
    const int gx = gridDim.x, gy = gridDim.y;
    if ((gy & 7) == 0) {
      const int f = by * gx + bx;
      const int j = f & 7;
      const int u = f >> 3;
      bx = u % gx;
      by = j * (gy >> 3) + u / gx;
    }
  }

  const int tid  = threadIdx.x;
  const int lane = tid & 63, wave = tid >> 6;
  const int wm   = wave >> 2, wn = wave & 3;
  const int ln   = lane & 15, quad = lane >> 4;
  const int t6   = tid >> 3, tA = t6 >> 5, t5 = t6 & 31;
  const int gc8  = ((tid & 7) ^ (t6 & 7)) * 8;
  const int pco  = (quad ^ (ln & 7)) * 8;
  const int aoff = (wm * 64 + ln) * 64 + pco;
  const int boff = (wn * 32 + ln) * 64 + pco;

  const long m0  = (long)by * 256;
  const int  n0g = bx * 256;
  const __bf16* Aa = Ag + m0 * K + koff + abat;
  const __bf16* Bb = Bg + (long)bx * 256 * K + koff + bbat +
                     ((MODE == 8) ? (long)(m0 >> 12) * sB : 0);

  f32x4 acc[8][4];
  const f32x4 zero = {0.f, 0.f, 0.f, 0.f};
#pragma unroll
  for (int i = 0; i < 8; i++)
#pragma unroll
    for (int j = 0; j < 4; j++) acc[i][j] = zero;

  // prologue: kt0 full (A0,B0 both halves) + kt1 (A1h0,B1h0) = 12 loads
  STG_A(LA0, 0, 0); STG_B(LB0, 0, 0);
  STG_A(LA0, 1, 0); STG_B(LB0, 1, 0);
  STG_A(LA1, 0, 1); STG_B(LB1, 0, 1);
  VMW(8);           // kt0 A0h0/B0h0 landed
  SBAR();

  const int niter = Klen >> 7;         // 2 K-tiles (of 64) per iteration
#pragma unroll 1
  for (int i = 0; i < niter - 1; ++i) {
    const int kb = i * 2;
    bf16x8 a[4][2], b[2][2], b1[2][2];
    PH(VMW(4), STG_A(LA1,1,kb+1), RD_A(a,LA0,0) RD_B(b,LB0,0), MM(0,0,a,b));
    PH(      , STG_B(LB1,1,kb+1), RD_B(b1,LB0,1),              MM(0,1,a,b1));
    PH(      , STG_A(LA0,0,kb+2), RD_A(a,LA0,1),               MM(1,1,a,b1));
    PH(VMW(6), STG_B(LB0,0,kb+2), ,                            MM(1,0,a,b));
    PH(VMW(4), STG_A(LA0,1,kb+2), RD_A(a,LA1,0) RD_B(b,LB1,0), MM(0,0,a,b));
    PH(      , STG_B(LB0,1,kb+2), RD_B(b1,LB1,1),              MM(0,1,a,b1));
    PH(      , STG_A(LA1,0,kb+3), RD_A(a,LA1,1),               MM(1,1,a,b1));
    PH(VMW(6), STG_B(LB1,0,kb+3), ,                            MM(1,0,a,b));
  }
  { // peeled last iteration: no stages beyond kt = 2*niter-1; drain at ph4
    const int kb = (niter - 1) * 2;
    bf16x8 a[4][2], b[2][2], b1[2][2];
    PH(VMW(4), STG_A(LA1,1,kb+1), RD_A(a,LA0,0) RD_B(b,LB0,0), MM(0,0,a,b));
    PH(      , STG_B(LB1,1,kb+1), RD_B(b1,LB0,1),              MM(0,1,a,b1));
    PH(      , ,                  RD_A(a,LA0,1),               MM(1,1,a,b1));
    PH(VMW(0), ,                  ,                            MM(1,0,a,b));
    PH(      , ,                  RD_A(a,LA1,0) RD_B(b,LB1,0), MM(0,0,a,b));
    PH(      , ,                  RD_B(b1,LB1,1),              MM(0,1,a,b1));
    PH(      , ,                  RD_A(a,LA1,1),               MM(1,1,a,b1));
    PH(      , ,                  ,                            MM(1,0,a,b));
    SBAR();   // all waves' K-loop LDS reads done before epilogue reuses LDS
  }

  // epilogue: C/D layout col = lane&15, row = quad*4 + reg (m89-verified)
  if (MODE == 6) {
    // transposed dual store: per m-half pass, tile -> LDS [n][s] -> [d][s]
    const bool isK = (n0g < 1024);
    const float* bb = isK ? bias : bias2;
    const int nb = isK ? n0g : (n0g - 1024);
    const int b = (int)(m0 >> 12);
    const long s_in = m0 & 4095;
    __bf16* dst = (__bf16*)(isK ? Cg : Cg2) + (long)b * DD * SS;
#pragma unroll
    for (int h = 0; h < 2; ++h) {
      if (wm == h) {
#pragma unroll
        for (int mf = 0; mf < 8; ++mf)
#pragma unroll
          for (int nf = 0; nf < 4; ++nf) {
            const int nl = wn * 64 + nf * 16 + ln;      // 0..255
            const int sl0 = mf * 16 + quad * 4;         // 0..124, mult of 4
            const float bv = bb[nb + nl];
            bf16x4 pk;
#pragma unroll
            for (int r = 0; r < 4; ++r) {
              float x = acc[mf][nf][r] + bv;
              if (isK) x = (x > 0.f) ? (x + 1.f) : __expf(x);
              pk[r] = f2bf(x);
            }
            *(bf16x4*)(sm.T + nl * 136 + sl0) = pk;     // 8B aligned (136*2B)
          }
      }
      __syncthreads();
#pragma unroll
      for (int p2 = 0; p2 < 8; ++p2) {
        const int row = (tid >> 4) + p2 * 32;           // n within tile
        const int c   = (tid & 15) * 8;                 // s chunk (128 wide)
        bf16x8 vv = *(const bf16x8*)(sm.T + row * 136 + c);
        *(bf16x8*)&dst[(long)(nb + row) * SS + s_in + h * 128 + c] = vv;
      }
      __syncthreads();
    }
    return;
  }

  const long zoff = (MODE == 5) ? (long)zid * DD * (long)DD : 0;
#pragma unroll
  for (int mf = 0; mf < 8; ++mf)
#pragma unroll
    for (int nf = 0; nf < 4; ++nf)
#pragma unroll
      for (int r = 0; r < 4; ++r) {
        const long gm = m0 + wm * 128 + mf * 16 + quad * 4 + r;
        const int  gn = n0g + wn * 64 + nf * 16 + ln;
        float x = acc[mf][nf][r];
        if (MODE == 0) {
          x += bias[gn];
          x = (x > 0.f) ? (x + 1.f) : __expf(x);
          ((__bf16*)Cg)[gm * (long)N + gn] = f2bf(x);
        } else if (MODE == 5) {
          ((float*)Cg)[zoff + gm * (long)N + gn] = x;
        } else {           // MODE 8
          x = x * zvec[gm] + bias[gn];
          ((float*)Cg)[gm * (long)N + gn] = x + resid[gm * (long)N + gn];
        }
      }
}

#undef PH
#undef MM
#undef RD_A
#undef RD_B
#undef STG_A
#undef STG_B

// ---------------------------------------------------------------------------
// 128x128-tile GEMM (2-barrier structure) — kept for mode 7.
// MODE: 7 = plain->bf16 (M2 = kv@Wo, stored as M2T[f][d])
// ---------------------------------------------------------------------------
template<int MODE>
__global__ __launch_bounds__(256)
void gemm_bt(const __bf16* __restrict__ Ag, const __bf16* __restrict__ Bg,
             void* __restrict__ Cg, void* __restrict__ Cg2,
             int N, int K, long sA, long sB, long sC,
             const float* __restrict__ bias, const float* __restrict__ bias2,
             const float* __restrict__ zvec,
             const float* __restrict__ resid)
{
  union SMem {
    struct { __bf16 As[128 * 64]; __bf16 Bs[128 * 64]; } s;  // 32 KB
    __bf16 T[128 * 136];                                     // 34 KB (epilogue)
  };
  __shared__ SMem sm;

  int bx = blockIdx.x, by = blockIdx.y;
  {
    const int gx = gridDim.x, gy = gridDim.y;
    if ((gy & 7) == 0) {
      const int f = by * gx + bx;
      const int j = f & 7;
      const int u = f >> 3;
      bx = u % gx;
      by = j * (gy >> 3) + u / gx;
    }
  }
  const int bz = blockIdx.z;

  const int tid = threadIdx.x;
  const long m0 = (long)by * 128;
  const __bf16* A = Ag + m0 * K + bz * sA;
  const __bf16* B = Bg + (long)bx * 128 * K + bz * sB;

  const int srow = tid >> 3;                   // 0..31
  const int gcc8 = ((tid & 7) ^ (srow & 7)) * 8;

  const int lane = tid & 63;
  const int wave = tid >> 6;
  const int wm   = (wave >> 1) * 64;
  const int wn   = (wave & 1) * 64;
  const int ln   = lane & 15;
  const int quad = lane >> 4;
  const int rk   = ln & 7;

  f32x4 acc[4][4];
  const f32x4 zero = {0.f, 0.f, 0.f, 0.f};
#pragma unroll
  for (int i = 0; i < 4; i++)
#pragma unroll
    for (int j = 0; j < 4; j++) acc[i][j] = zero;

  for (int k0 = 0; k0 < K; k0 += 64) {
#pragma unroll
    for (int p = 0; p < 4; p++) {
      async_load16(A + (long)(p * 32 + srow) * K + k0 + gcc8, sm.s.As + p * 2048 + tid * 8);
      async_load16(B + (long)(p * 32 + srow) * K + k0 + gcc8, sm.s.Bs + p * 2048 + tid * 8);
    }
    __syncthreads();

#pragma unroll
    for (int ksub = 0; ksub < 2; ksub++) {
      const int cc = (ksub * 4 + quad) ^ rk;
      bf16x8 af[4], bfr[4];
#pragma unroll
      for (int i = 0; i < 4; i++)
        af[i] = *(const bf16x8*)(sm.s.As + (wm + i * 16 + ln) * 64 + cc * 8);
#pragma unroll
      for (int j = 0; j < 4; j++)
        bfr[j] = *(const bf16x8*)(sm.s.Bs + (wn + j * 16 + ln) * 64 + cc * 8);
#pragma unroll
      for (int i = 0; i < 4; i++)
#pragma unroll
        for (int j = 0; j < 4; j++)
          acc[i][j] = __builtin_amdgcn_mfma_f32_16x16x32_bf16(af[i], bfr[j], acc[i][j], 0, 0, 0);
    }
    __syncthreads();
  }

  const int n0g = bx * 128;
#pragma unroll
  for (int i = 0; i < 4; i++) {
#pragma unroll
    for (int j = 0; j < 4; j++) {
#pragma unroll
      for (int r = 0; r < 4; r++) {
        const int lrow = wm + i * 16 + quad * 4 + r;
        const int lcol = wn + j * 16 + ln;
        const long gm  = m0 + lrow;
        const int  gn  = n0g + lcol;
        if (MODE == 7) {
          ((__bf16*)Cg)[(long)bz * sC + gm * (long)N + gn] = f2bf(acc[i][j][r]);
        }
      }
    }
  }
}

// ---------------------------------------------------------------------------
__global__ __launch_bounds__(256)
void cvt_f32_bf16(const float* __restrict__ x, __bf16* __restrict__ y, long n)
{
  long i = ((long)blockIdx.x * 256 + threadIdx.x) * 4;
  if (i < n) {
    float4 v = *(const float4*)(x + i);
    bf16x4 o;
    o[0] = f2bf(v.x); o[1] = f2bf(v.y); o[2] = f2bf(v.z); o[3] = f2bf(v.w);
    *(bf16x4*)(y + i) = o;
  }
}

// ---------------------------------------------------------------------------
// kvbf[b][i] = bf16( sum_{s=0..3} kvf[(b*4+s)][i] )   (i over 1M floats)
// ---------------------------------------------------------------------------
__global__ __launch_bounds__(256)
void reduce4_bf16(const float* __restrict__ kvf, __bf16* __restrict__ kvbf)
{
  const long g = (long)blockIdx.x * 256 + threadIdx.x;   // float4 index
  const int  b = (int)(g >> 18);                          // 262144 float4/batch
  const long i = (g & 262143L) * 4;
  const float* p = kvf + (long)b * 4194304 + i;
  float4 s0 = *(const float4*)(p);
  float4 s1 = *(const float4*)(p + 1048576);
  float4 s2 = *(const float4*)(p + 2097152);
  float4 s3 = *(const float4*)(p + 3145728);
  bf16x4 o;
  o[0] = f2bf(s0.x + s1.x + s2.x + s3.x);
  o[1] = f2bf(s0.y + s1.y + s2.y + s3.y);
  o[2] = f2bf(s0.z + s1.z + s2.z + s3.z);
  o[3] = f2bf(s0.w + s1.w + s2.w + s3.w);
  *(bf16x4*)(kvbf + (long)b * 1048576 + i) = o;
}

// ---------------------------------------------------------------------------
// Weight transpose + convert: W fp32 [D][D] -> WT bf16 [D][D]; 4 weights via z
// ---------------------------------------------------------------------------
__global__ __launch_bounds__(256)
void wtrans(const float* W0, const float* W1, const float* W2, const float* W3,
            __bf16* O0, __bf16* O1, __bf16* O2, __bf16* O3, int Dd)
{
  __shared__ __bf16 t[64][72];
  const float* W = (blockIdx.z == 0) ? W0 : (blockIdx.z == 1) ? W1 : (blockIdx.z == 2) ? W2 : W3;
  __bf16*      O = (blockIdx.z == 0) ? O0 : (blockIdx.z == 1) ? O1 : (blockIdx.z == 2) ? O2 : O3;
  const int r0 = blockIdx.y * 64, c0 = blockIdx.x * 64;
  const int tid = threadIdx.x;
  const int lr4 = tid >> 4, lc4 = (tid & 15) * 4;
#pragma unroll
  for (int it = 0; it < 4; it++) {
    const int row = lr4 + it * 16;
    float4 v = *(const float4*)&W[(long)(r0 + row) * Dd + c0 + lc4];
    t[row][lc4 + 0] = f2bf(v.x);
    t[row][lc4 + 1] = f2bf(v.y);
    t[row][lc4 + 2] = f2bf(v.z);
    t[row][lc4 + 3] = f2bf(v.w);
  }
  __syncthreads();
  const int lr8 = tid >> 3, lc8 = (tid & 7) * 8;
#pragma unroll
  for (int it = 0; it < 2; it++) {
    const int orow = lr8 + it * 32;
    bf16x8 vb;
#pragma unroll
    for (int j = 0; j < 8; j++) vb[j] = t[lc8 + j][orow];
    *(bf16x8*)&O[(long)(c0 + orow) * Dd + r0 + lc8] = vb;
  }
}

// ---------------------------------------------------------------------------
// k_sum[b*D+d] = sum_s kphiT[(b*D+d)*S + s]
// ---------------------------------------------------------------------------
__global__ __launch_bounds__(256)
void ksum_k(const __bf16* __restrict__ kphiT, float* __restrict__ ksum, int S)
{
  const long row = blockIdx.x;
  const __bf16* p = kphiT + row * (long)S;
  const int tid = threadIdx.x;
  float s = 0.f;
  for (int j = tid * 8; j < S; j += 256 * 8) {
    bf16x8 v = *(const bf16x8*)&p[j];
#pragma unroll
    for (int e = 0; e < 8; e++) s += (float)v[e];
  }
  __shared__ float red[256];
  red[tid] = s; __syncthreads();
  for (int off = 128; off > 0; off >>= 1) {
    if (tid < off) red[tid] += red[tid + off];
    __syncthreads();
  }
  if (tid == 0) ksum[row] = red[0];
}

// ---------------------------------------------------------------------------
// z[b*S+s] = 1 / (q_phi[row] . k_sum[b] + 1e-6)
// ---------------------------------------------------------------------------
__global__ __launch_bounds__(256)
void zden_k(const __bf16* __restrict__ qphi, const float* __restrict__ ksum,
            float* __restrict__ z, int Dd, int S)
{
  const long row = blockIdx.x;
  const int  b   = (int)(row / S);
  const __bf16* q = qphi + row * (long)Dd;
  const float* ks = ksum + (long)b * Dd;
  const int tid = threadIdx.x;
  const int i = tid * 4;                      // Dd = 1024 = 256*4 exactly
  bf16x4 qv = *(const bf16x4*)&q[i];
  float4 kv4 = *(const float4*)&ks[i];
  float s = (float)qv[0] * kv4.x + (float)qv[1] * kv4.y +
            (float)qv[2] * kv4.z + (float)qv[3] * kv4.w;
  __shared__ float red[256];
  red[tid] = s; __syncthreads();
  for (int off = 128; off > 0; off >>= 1) {
    if (tid < off) red[tid] += red[tid + off];
    __syncthreads();
  }
  if (tid == 0) z[row] = 1.f / (red[0] + 1e-6f);
}

// ---------------------------------------------------------------------------
extern "C" void kernel_launch(void* const* d_in, const int* in_sizes, int n_in,
                              void* d_out, int out_size, void* d_ws, size_t ws_size,
                              hipStream_t stream)
{
  const float* inputs  = (const float*)d_in[0];
  const float* context = (const float*)d_in[1];
  const float* Wq = (const float*)d_in[2];
  const float* bq = (const float*)d_in[3];
  const float* Wk = (const float*)d_in[4];
  const float* bk = (const float*)d_in[5];
  const float* Wv = (const float*)d_in[6];
  const float* bv = (const float*)d_in[7];
  const float* Wo = (const float*)d_in[8];
  const float* bo = (const float*)d_in[9];
  float* out = (float*)d_out;

  const int Bn = 4;
  const long NSD = (long)Bn * SS * DD;         // 16,777,216
  const long MB = 1L << 20;

  char* ws = (char*)d_ws;
  __bf16* xbf   = (__bf16*)(ws + 0 * MB);      // 32 MB (dead after step 2)
  __bf16* cbf   = (__bf16*)(ws + 32 * MB);     // 32 MB (dead after step 3)
  float*  kvf   = (float*)(ws + 0 * MB);       // 64 MB, ALIASES xbf+cbf:
                                               //   16 slabs [b*4+s][1M] f32
  __bf16* qphi  = (__bf16*)(ws + 64 * MB);     // 32 MB
  __bf16* kphiT = (__bf16*)(ws + 96 * MB);     // 32 MB   [b][D][S]
  __bf16* vT    = (__bf16*)(ws + 128 * MB);    // 32 MB   [b][D][S]
  __bf16* kvbf  = (__bf16*)(ws + 176 * MB);    // 8 MB    [b][D][D]
  __bf16* M2T   = (__bf16*)(ws + 184 * MB);    // 8 MB    [b][D][D]  (kv@Wo)^T
  __bf16* WqT   = (__bf16*)(ws + 192 * MB);    // 2 MB each; WkT/WvT contiguous!
  __bf16* WkT   = (__bf16*)(ws + 194 * MB);
  __bf16* WvT   = (__bf16*)(ws + 196 * MB);
  __bf16* WoT   = (__bf16*)(ws + 198 * MB);
  float*  ksum  = (float*)(ws + 200 * MB);
  float*  zbuf  = (float*)(ws + 201 * MB);

  // 1) converts
  cvt_f32_bf16<<<16384, 256, 0, stream>>>(inputs,  xbf, NSD);
  cvt_f32_bf16<<<16384, 256, 0, stream>>>(context, cbf, NSD);
  wtrans<<<dim3(16, 16, 4), 256, 0, stream>>>(Wq, Wk, Wv, Wo, WqT, WkT, WvT, WoT, DD);

  // 2) q projection: qphi = phi(x Wq + bq), row-major [B*S][D]
  gemm256<0><<<dim3(4, 64), 512, 0, stream>>>(xbf, WqT, qphi, nullptr,
      DD, DD, DD, 0, 0, bq, nullptr, nullptr, nullptr);

  // 3) fused k/v projection (N=2048, WkT||WvT contiguous), transposed outputs
  gemm256<6><<<dim3(8, 64), 512, 0, stream>>>(cbf, WkT, kphiT, vT,
      2048, DD, DD, 0, 0, bk, bv, nullptr, nullptr);

  // 4) k_sum and z
  ksum_k<<<4096, 256, 0, stream>>>(kphiT, ksum, SS);
  zden_k<<<16384, 256, 0, stream>>>(qphi, ksum, zbuf, DD, SS);

  // 5) kv[b][d][e] = sum_s kphiT[b][d][s] * vT[b][e][s]
  //    split-K(4) plain f32 partial slabs (overwrites dead xbf/cbf) + reduce
  gemm256<5><<<dim3(4, 4, 16), 512, 0, stream>>>(kphiT, vT, kvf, nullptr,
      DD, SS, DD, (long)DD * SS, (long)DD * SS,
      nullptr, nullptr, nullptr, nullptr);
  reduce4_bf16<<<4096, 256, 0, stream>>>(kvf, kvbf);

  // 6) M2T[b][f][d] = sum_e WoT[f][e] * kv[b][d][e]   (tiny: 8.6 GF)
  gemm_bt<7><<<dim3(8, 8, 4), 256, 0, stream>>>(WoT, kvbf, M2T, nullptr,
      DD, DD, 0, (long)DD * DD, (long)DD * DD, nullptr, nullptr, nullptr, nullptr);

  // 7) out[s][f] = z[s] * (sum_d qphi[s][d] * M2T[b][f][d]) + bo[f] + x[s][f]
  gemm256<8><<<dim3(4, 64), 512, 0, stream>>>(qphi, M2T, out, nullptr,
      DD, DD, DD, 0, (long)DD * DD, bo, nullptr, zbuf, inputs);
}